// Round 7
// baseline (304.067 us; speedup 1.0000x reference)
//
#include <hip/hip_runtime.h>

// Exact-match lookup of 4M int32 queries in a sorted 8M int32 key table.
// Round 7: bin-partition + LDS-window join, with XCD-privatized pair regions.
//
// Round-6 lesson: scattered 8B pair writes into a shared region are written
// as partial 64B lines by 8 non-coherent per-XCD L2s -> 8x write
// amplification (263 MB for 32 MB of pairs, 1.65 TB/s). Fix: pairs[g][bin]
// with g = blockIdx & 7; under the round-robin blockIdx->XCD mapping all
// writes to a group's region come from one XCD, so tail lines fill fully in
// one L2 before eviction. If the mapping assumption breaks it is only slower,
// never incorrect.
//
// Pipeline:
//  K1 index : bstart[b] = lower_bound(keys, b<<SHIFT); zero cursors/ovf.
//  K2 scatter: query i -> bin b = (unsigned)q >> SHIFT, group g = blockIdx&7;
//              slot = atomicAdd(cursor[g][b]); pairs[g][b][slot] = (q, i).
//              Invalid bin (q can't be in table) -> out[i] = -1 directly.
//              Slot >= CAPG -> overflow list (statistically never).
//  K3 join  : one block per bin; stage the bin's sorted key window (<=12288
//             keys, 48 KB) in LDS; for each (q, i) in the bin's 8 segments,
//             LDS lower_bound -> out[i] = match ? vals[wlo+l] : -1.
//             Window > WMAX (never: avg 8192, sigma~90) -> global bsearch.
//  K4 ovf   : global bsearch for overflow-list queries.
//
// Exactly-once: every query goes to one of {pair slot, ovf list, direct out
// write}; join/ovf write out[orig] for each pair exactly once. Slot order
// within a bin is nondeterministic, but each query's result is independent of
// slot order -> out is deterministic. LDS lower_bound over the contiguous
// sorted window returns the FIRST match -> searchsorted-left semantics.

constexpr int LOGBINS = 10;
constexpr int NBINS   = 1 << LOGBINS;   // 1024 bins
constexpr int SHIFT   = 31 - LOGBINS;   // bin = (unsigned)q >> 21
constexpr int NGRP    = 8;              // XCD privatization groups
constexpr int LOGCAPG = 10;
constexpr int CAPG    = 1 << LOGCAPG;   // slots per (group,bin); avg load 512
constexpr int WMAX    = 12288;          // LDS key-window capacity (48 KB)

__device__ __forceinline__ int lower_bound_g(const int* __restrict__ keys,
                                             int lo, int hi, unsigned t) {
    while (lo < hi) {
        int m = (lo + hi) >> 1;
        if ((unsigned)keys[m] < t) lo = m + 1; else hi = m;
    }
    return lo;
}

// K1: per-bin key-window index + zero cursors and overflow counter.
__global__ void index_kernel(const int* __restrict__ keys, int K,
                             int* __restrict__ bstart,
                             int* __restrict__ cursor,
                             int* __restrict__ ovf_count) {
    int i = blockIdx.x * blockDim.x + threadIdx.x;
    if (i <= NBINS) bstart[i] = lower_bound_g(keys, 0, K, ((unsigned)i) << SHIFT);
    if (i < NGRP * NBINS) cursor[i] = 0;
    if (i == 0) *ovf_count = 0;
}

// K2: scatter (query, orig_idx) into its (group, bin) segment.
__global__ void scatter_kernel(const int* __restrict__ query, int N,
                               int* __restrict__ cursor,
                               int2* __restrict__ pairs,
                               int* __restrict__ ovf_count,
                               int2* __restrict__ ovf,
                               int* __restrict__ out) {
    int t = blockIdx.x * blockDim.x + threadIdx.x;
    int g = blockIdx.x & (NGRP - 1);   // round-robin blockIdx -> XCD
    int i4 = t * 4;

    auto put = [&](int q, int idx) {
        unsigned b = ((unsigned)q) >> SHIFT;
        if (b >= (unsigned)NBINS) { out[idx] = -1; return; }  // cannot match
        int c = g * NBINS + (int)b;
        int slot = atomicAdd(&cursor[c], 1);
        if (slot < CAPG) pairs[((size_t)c << LOGCAPG) + slot] = make_int2(q, idx);
        else { int p = atomicAdd(ovf_count, 1); ovf[p] = make_int2(q, idx); }
    };

    if (i4 + 3 < N) {
        int4 qv = *reinterpret_cast<const int4*>(query + i4);
        put(qv.x, i4); put(qv.y, i4 + 1); put(qv.z, i4 + 2); put(qv.w, i4 + 3);
    } else if (i4 < N) {
        for (int i = i4; i < N; ++i) put(query[i], i);
    }
}

// K3: one block per bin — LDS key window + binary search each binned query.
__global__ void __launch_bounds__(512) join_kernel(
        const int* __restrict__ keys, const int* __restrict__ vals, int K,
        const int* __restrict__ bstart, const int* __restrict__ cursor,
        const int2* __restrict__ pairs, int* __restrict__ out) {
    __shared__ unsigned s_keys[WMAX];
    int b = blockIdx.x;
    int wlo = bstart[b], whi = bstart[b + 1];
    int wn = whi - wlo;
    bool use_lds = (wn <= WMAX);   // block-uniform
    if (use_lds) {
        for (int j = threadIdx.x; j < wn; j += 512)
            s_keys[j] = (unsigned)keys[wlo + j];
    }
    __syncthreads();

    for (int g = 0; g < NGRP; ++g) {
        int c = g * NBINS + b;
        int cnt = cursor[c];
        if (cnt > CAPG) cnt = CAPG;
        const int2* bp = pairs + ((size_t)c << LOGCAPG);
        for (int j = threadIdx.x; j < cnt; j += 512) {
            int2 p = bp[j];
            unsigned q = (unsigned)p.x;
            int r = -1;
            if (use_lds) {
                int l = 0, h = wn;
                while (l < h) {
                    int m = (l + h) >> 1;
                    if (s_keys[m] < q) l = m + 1; else h = m;
                }
                if (l < wn && s_keys[l] == q) r = vals[wlo + l];
            } else {  // statistically-never: window too big for LDS
                int l = lower_bound_g(keys, wlo, whi, q);
                if (l < whi && (unsigned)keys[l] == q) r = vals[l];
            }
            out[p.y] = r;
        }
    }
}

// K4: overflow queries — global binary search. ~Never runs.
__global__ void ovf_kernel(const int2* __restrict__ ovf,
                           const int* __restrict__ ovf_count,
                           const int* __restrict__ keys,
                           const int* __restrict__ vals, int K,
                           int* __restrict__ out) {
    int n = *ovf_count;
    for (int i = blockIdx.x * blockDim.x + threadIdx.x; i < n;
         i += gridDim.x * blockDim.x) {
        int2 p = ovf[i];
        unsigned q = (unsigned)p.x;
        int l = lower_bound_g(keys, 0, K, q);
        int r = -1;
        if (l < K && (unsigned)keys[l] == q) r = vals[l];
        out[p.y] = r;
    }
}

// Fallback for tiny workspace: plain binary search per query.
__global__ void lookup_bsearch_kernel(const int* __restrict__ query,
                                      const int* __restrict__ keys,
                                      const int* __restrict__ vals,
                                      int* __restrict__ out,
                                      int N, int K) {
    int i = blockIdx.x * blockDim.x + threadIdx.x;
    if (i >= N) return;
    unsigned q = (unsigned)query[i];
    int lo = lower_bound_g(keys, 0, K, q);
    int r = -1;
    if (lo < K && (unsigned)keys[lo] == q) r = vals[lo];
    out[i] = r;
}

extern "C" void kernel_launch(void* const* d_in, const int* in_sizes, int n_in,
                              void* d_out, int out_size, void* d_ws, size_t ws_size,
                              hipStream_t stream) {
    const int* query = (const int*)d_in[0];
    const int* keys  = (const int*)d_in[1];
    const int* vals  = (const int*)d_in[2];
    int* out = (int*)d_out;
    const int N = in_sizes[0];
    const int K = in_sizes[1];
    const int tb = 256;

    // Workspace layout (16B-aligned):
    //   pairs  : NGRP*NBINS*CAPG int2  = 64 MB
    //   bstart : (NBINS+1) int
    //   cursor : NGRP*NBINS int
    //   ovfcnt : 1 int (padded)
    //   ovf    : N int2                = 32 MB
    size_t off = 0;
    int2* pairs = (int2*)((char*)d_ws + off);
    off += (size_t)NGRP * NBINS * CAPG * sizeof(int2);
    int* bstart = (int*)((char*)d_ws + off);
    off += ((size_t)(NBINS + 1) * 4 + 15) & ~(size_t)15;
    int* cursor = (int*)((char*)d_ws + off);
    off += ((size_t)NGRP * NBINS * 4 + 15) & ~(size_t)15;
    int* ovf_count = (int*)((char*)d_ws + off);
    off += 16;
    int2* ovf = (int2*)((char*)d_ws + off);
    off += (size_t)N * sizeof(int2);

    if (off <= ws_size) {
        int idx_threads = NGRP * NBINS;  // covers NBINS+1 too
        index_kernel<<<(idx_threads + tb - 1) / tb, tb, 0, stream>>>(
            keys, K, bstart, cursor, ovf_count);
        int nq4 = (N + 3) / 4;
        scatter_kernel<<<(nq4 + tb - 1) / tb, tb, 0, stream>>>(
            query, N, cursor, pairs, ovf_count, ovf, out);
        join_kernel<<<NBINS, 512, 0, stream>>>(keys, vals, K, bstart, cursor,
                                               pairs, out);
        ovf_kernel<<<64, tb, 0, stream>>>(ovf, ovf_count, keys, vals, K, out);
    } else {
        lookup_bsearch_kernel<<<(N + tb - 1) / tb, tb, 0, stream>>>(query, keys,
                                                                    vals, out, N, K);
    }
}

// Round 8
// 135.954 us; speedup vs baseline: 2.2365x; 2.2365x over previous
//
#include <hip/hip_runtime.h>

// Exact-match lookup of 4M int32 queries in a sorted 8M int32 key table.
// Round 8: round-5 gather pipeline (index -> build packed table -> lookup),
// with the build rewritten as a rank-scatter: no per-thread binary search,
// no divergent pack loop. Each block owns 256 buckets; the block's key
// window (avg 256 keys) is staged in LDS; bucket-first indices and per-key
// ranks are derived with unique-writer LDS stores; the 4 KB table slice is
// emitted with fully coalesced 16B stores.
//
// Table: B = 2^23 buckets (bucket = (unsigned)key >> 8), 16 B/bucket = 128 MB.
// Entry = 4 x 32-bit slots; keys in a bucket share bits [30:8]:
//   bits[31:28] flags: 0=empty, 1=valid pair, 2=overflow descriptor (word0)
//   bits[27:8]  value (build verifies 0 <= val < 2^20, else overflow)
//   bits[7:0]   low 8 bits of key
// Overflow (count>4 or value out of range): word0 = 2<<28, word1 = start
// index into keys/vals; lookup scans forward with early exit on key >= q.
// Slots filled in sorted order, checked in order -> searchsorted-left
// semantics for duplicate keys. Queries are >= 1 so empty slots (0) never
// false-match.

constexpr int WCAP = 1024;     // LDS window capacity per 256-bucket block
constexpr int NBLK = 1 << 15;  // 32768 build blocks (256 buckets each)

__device__ __forceinline__ int lower_bound_u(const int* __restrict__ keys,
                                             int lo, int hi, unsigned t) {
    while (lo < hi) {
        int m = (lo + hi) >> 1;
        if ((unsigned)keys[m] < t) lo = m + 1; else hi = m;
    }
    return lo;
}

// K1: bstart[i] = lower_bound(keys, (i*256)<<8), i in [0, NBLK] inclusive.
// Independent threads -> latency fully hidden across waves.
__global__ void block_index_kernel(const int* __restrict__ keys, int K,
                                   int* __restrict__ bstart) {
    int i = blockIdx.x * blockDim.x + threadIdx.x;
    if (i > NBLK) return;
    bstart[i] = lower_bound_u(keys, 0, K, ((unsigned)i) << 16);
}

// K2: rank-scatter build. One block = 256 buckets.
__global__ void __launch_bounds__(256) build_rank_kernel(
        const int* __restrict__ keys, const int* __restrict__ vals, int K,
        const int* __restrict__ bstart, int4* __restrict__ table) {
    __shared__ int s_keys[WCAP];
    __shared__ int s_vals[WCAP];
    __shared__ int s_first[256];
    __shared__ int s_flag[256];
    __shared__ int s_ent[256][4];

    const int tid = threadIdx.x;
    const int wlo = bstart[blockIdx.x];
    const int whi = bstart[blockIdx.x + 1];
    const int wn = whi - wlo;
    const unsigned base_b = (unsigned)blockIdx.x << 8;  // first bucket of block

    // init
    s_flag[tid] = 0;
    s_ent[tid][0] = 0; s_ent[tid][1] = 0; s_ent[tid][2] = 0; s_ent[tid][3] = 0;

    if (wn <= WCAP) {
        // stage window (coalesced)
        for (int j = tid; j < wn; j += 256) {
            s_keys[j] = keys[wlo + j];
            s_vals[j] = vals[wlo + j];
        }
        __syncthreads();

        // pass B: mark first window-index of each bucket (unique writer per bucket)
        for (int j = tid; j < wn; j += 256) {
            unsigned b = ((unsigned)s_keys[j]) >> 8;
            bool first = (j == 0) || ((((unsigned)s_keys[j - 1]) >> 8) != b);
            if (first) s_first[b & 255u] = j;
        }
        __syncthreads();

        // pass C: rank-scatter packed words (unique (bucket,rank) writer per key)
        for (int j = tid; j < wn; j += 256) {
            int k = s_keys[j];
            unsigned lb = (((unsigned)k) >> 8) & 255u;
            int rank = j - s_first[lb];
            int v = s_vals[j];
            if (rank < 4 && (unsigned)v <= 0xFFFFFu) {
                s_ent[lb][rank] = (1 << 28) | (v << 8) | (k & 0xFF);
            } else {
                s_flag[lb] = 1;  // benign same-value multi-writer
            }
        }
        __syncthreads();

        // pass D: emit (coalesced 16B stores, 4 KB contiguous per block)
        int4 e;
        if (s_flag[tid]) e = make_int4(2 << 28, wlo + s_first[tid], 0, 0);
        else             e = make_int4(s_ent[tid][0], s_ent[tid][1],
                                       s_ent[tid][2], s_ent[tid][3]);
        table[base_b + tid] = e;
    } else {
        // statistically-never fallback: window too big for LDS -> per-thread
        // global search/pack (correct, slow).
        __syncthreads();
        unsigned b = base_b + tid;
        unsigned tlo = b << 8;
        unsigned thi = tlo + 256u;
        int lo = lower_bound_u(keys, wlo, whi, tlo);
        int w[4] = {0, 0, 0, 0};
        bool ok = true;
        int cnt = 0;
        int j = lo;
        while (j < whi && (unsigned)keys[j] < thi) {
            if (cnt >= 4) { ok = false; break; }
            int v = vals[j];
            if ((unsigned)v > 0xFFFFFu) { ok = false; break; }
            w[cnt] = (1 << 28) | (v << 8) | (keys[j] & 0xFF);
            ++cnt; ++j;
        }
        table[b] = ok ? make_int4(w[0], w[1], w[2], w[3])
                      : make_int4(2 << 28, lo, 0, 0);
    }
}

__device__ __forceinline__ int resolve_packed(int q, int4 e,
                                              const int* __restrict__ keys,
                                              const int* __restrict__ vals,
                                              int K) {
    if ((((unsigned)e.x) >> 28) == 2u) {  // overflow: scan original arrays
        for (int j = e.y; j < K; ++j) {
            int k = keys[j];
            if ((unsigned)k >= (unsigned)q) return (k == q) ? vals[j] : -1;
        }
        return -1;
    }
    int ql = q & 0xFF;
    int w;
    w = e.x; if ((((unsigned)w) >> 28) == 1u && (w & 0xFF) == ql) return (w >> 8) & 0xFFFFF;
    w = e.y; if ((((unsigned)w) >> 28) == 1u && (w & 0xFF) == ql) return (w >> 8) & 0xFFFFF;
    w = e.z; if ((((unsigned)w) >> 28) == 1u && (w & 0xFF) == ql) return (w >> 8) & 0xFFFFF;
    w = e.w; if ((((unsigned)w) >> 28) == 1u && (w & 0xFF) == ql) return (w >> 8) & 0xFFFFF;
    return -1;
}

// K3: lookup — 2 independent probe chains per thread, coalesced out writes.
__global__ void lookup_packed_kernel(const int* __restrict__ query,
                                     const int* __restrict__ keys,
                                     const int* __restrict__ vals,
                                     const int4* __restrict__ table,
                                     int* __restrict__ out,
                                     int N, int K, unsigned Bmask) {
    int half = (N + 1) >> 1;
    int i = blockIdx.x * blockDim.x + threadIdx.x;
    if (i >= half) return;
    int i1 = i + half;
    bool has1 = (i1 < N);
    int q0 = query[i];
    int q1 = has1 ? query[i1] : q0;
    int4 e0 = table[(((unsigned)q0) >> 8) & Bmask];
    int4 e1 = table[(((unsigned)q1) >> 8) & Bmask];
    out[i] = resolve_packed(q0, e0, keys, vals, K);
    if (has1) out[i1] = resolve_packed(q1, e1, keys, vals, K);
}

// Fallback for tiny workspace: plain binary search (searchsorted 'left').
__global__ void lookup_bsearch_kernel(const int* __restrict__ query,
                                      const int* __restrict__ keys,
                                      const int* __restrict__ vals,
                                      int* __restrict__ out,
                                      int N, int K) {
    int i = blockIdx.x * blockDim.x + threadIdx.x;
    if (i >= N) return;
    unsigned q = (unsigned)query[i];
    int lo = lower_bound_u(keys, 0, K, q);
    int r = -1;
    if (lo < K && (unsigned)keys[lo] == q) r = vals[lo];
    out[i] = r;
}

extern "C" void kernel_launch(void* const* d_in, const int* in_sizes, int n_in,
                              void* d_out, int out_size, void* d_ws, size_t ws_size,
                              hipStream_t stream) {
    const int* query = (const int*)d_in[0];
    const int* keys  = (const int*)d_in[1];
    const int* vals  = (const int*)d_in[2];
    int* out = (int*)d_out;
    const int N = in_sizes[0];
    const int K = in_sizes[1];
    const int tb = 256;

    const size_t TABLE_BYTES = (size_t)16 << 23;       // 128 MB
    const size_t IDX_BYTES   = (size_t)(NBLK + 1) * 4; // ~128 KB

    if (TABLE_BYTES <= ws_size) {
        const unsigned B = 1u << 23;
        int4* table = (int4*)d_ws;
        // Block index: ws tail if it fits, else d_out (legal scratch: lookup
        // fully overwrites d_out afterwards; deterministic per call).
        int* bstart = (TABLE_BYTES + IDX_BYTES <= ws_size)
                          ? (int*)((char*)d_ws + TABLE_BYTES)
                          : (int*)d_out;
        block_index_kernel<<<(NBLK + 1 + tb - 1) / tb, tb, 0, stream>>>(keys, K, bstart);
        build_rank_kernel<<<NBLK, tb, 0, stream>>>(keys, vals, K, bstart, table);
        int half = (N + 1) >> 1;
        lookup_packed_kernel<<<(half + tb - 1) / tb, tb, 0, stream>>>(
            query, keys, vals, table, out, N, K, B - 1);
    } else {
        lookup_bsearch_kernel<<<(N + tb - 1) / tb, tb, 0, stream>>>(query, keys,
                                                                    vals, out, N, K);
    }
}